// Round 1
// baseline (192.249 us; speedup 1.0000x reference)
//
#include <hip/hip_runtime.h>
#include <hip/hip_bf16.h>

#define VOCAB 200000
#define EDIM  256

typedef __attribute__((ext_vector_type(4))) float  f32x4;
typedef __attribute__((ext_vector_type(8))) __bf16 bf16x8;

__device__ __forceinline__ __bf16 f2bf(float f) {
    unsigned u = __builtin_bit_cast(unsigned, f);
    u += 0x7FFFu + ((u >> 16) & 1u);           // round-to-nearest-even
    unsigned short s = (unsigned short)(u >> 16);
    return __builtin_bit_cast(__bf16, s);
}

// Pack B into MFMA fragment order.
// k = a*16 + b  (a = k>>4, b = k&15);  B[k][j] = core1[b, j, a], core1 is (16,256,16).
// Fragment for (kk, nt): lane l, elem e holds B[k = kk*32 + (l>>4)*8 + e][j = nt*16 + (l&15)].
// Stored as bpk[(kk*16 + nt)*64 + lane] (16B per lane -> coalesced dwordx4 loads).
__global__ void pack_b_kernel(const float* __restrict__ core1, bf16x8* __restrict__ bpk) {
    int t    = blockIdx.x * 256 + threadIdx.x;   // 0..8191
    int lane = t & 63;
    int nt   = (t >> 6) & 15;
    int kk   = t >> 10;
    int j     = nt * 16 + (lane & 15);
    int kbase = kk * 32 + ((lane >> 4) * 8);
    bf16x8 v;
#pragma unroll
    for (int e = 0; e < 8; ++e) {
        int k = kbase + e;
        int b = k & 15, a = k >> 4;
        v[e] = f2bf(core1[(b * 256 + j) * 16 + a]);
    }
    bpk[t] = v;
}

// One wave computes 16 gathered output rows x 256 cols.
// A[m][k] = core0[a, idx[m], b] with k = a*16+b: per k-step (K=32) each lane reads
// 8 contiguous floats of core0 (b-contiguous), converts to bf16.
__global__ __launch_bounds__(256) void tr_embed_kernel(
        const int* __restrict__ x, const float* __restrict__ core0,
        const bf16x8* __restrict__ bpk, float* __restrict__ out) {
    const int lane = threadIdx.x & 63;
    const int wave = threadIdx.x >> 6;
    const int rowBase = (blockIdx.x * 4 + wave) * 16;
    const int half = lane >> 4;            // 0..3
    const long idx = x[rowBase + (lane & 15)];

    // k-step kk: k_global = kk*32 + half*8 + e -> a = kk*2 + (half>>1), b = (half&1)*8 + e
    const float* aptr = core0 + ((long)(half >> 1) * VOCAB + idx) * 16 + (half & 1) * 8;
    const long kkStride = (long)2 * VOCAB * 16;   // a advances by 2 per k-step

    f32x4 acc[16] = {};

    f32x4 a0 = *(const f32x4*)(aptr);
    f32x4 a1 = *(const f32x4*)(aptr + 4);

    for (int kk = 0; kk < 8; ++kk) {
        f32x4 n0, n1;
        if (kk < 7) {                       // prefetch next k-step's A (HBM latency hide)
            n0 = *(const f32x4*)(aptr + (kk + 1) * kkStride);
            n1 = *(const f32x4*)(aptr + (kk + 1) * kkStride + 4);
        }
        bf16x8 af;
#pragma unroll
        for (int e = 0; e < 4; ++e) { af[e] = f2bf(a0[e]); af[e + 4] = f2bf(a1[e]); }

        const bf16x8* bp = bpk + (kk * 16) * 64 + lane;
#pragma unroll
        for (int nt = 0; nt < 16; ++nt) {
            bf16x8 bfr = bp[nt * 64];       // 16B coalesced, L2-resident
            acc[nt] = __builtin_amdgcn_mfma_f32_16x16x32_bf16(af, bfr, acc[nt], 0, 0, 0);
        }
        if (kk < 7) { a0 = n0; a1 = n1; }
    }

    // C/D layout (verified m89/m91): col = lane&15, row = (lane>>4)*4 + reg
    float* obase = out + (long)rowBase * 256 + (lane & 15);
#pragma unroll
    for (int nt = 0; nt < 16; ++nt) {
#pragma unroll
        for (int e = 0; e < 4; ++e) {
            obase[(half * 4 + e) * 256 + nt * 16] = acc[nt][e];
        }
    }
}

extern "C" void kernel_launch(void* const* d_in, const int* in_sizes, int n_in,
                              void* d_out, int out_size, void* d_ws, size_t ws_size,
                              hipStream_t stream) {
    const int*   x     = (const int*)d_in[0];
    const float* core0 = (const float*)d_in[1];
    const float* core1 = (const float*)d_in[2];
    float* out = (float*)d_out;
    bf16x8* bpk = (bf16x8*)d_ws;            // 128 KB scratch

    pack_b_kernel<<<32, 256, 0, stream>>>(core1, bpk);
    // 204800 rows / (4 waves * 16 rows) = 3200 blocks
    tr_embed_kernel<<<3200, 256, 0, stream>>>(x, core0, bpk, out);
}

// Round 2
// 167.004 us; speedup vs baseline: 1.1512x; 1.1512x over previous
//
#include <hip/hip_runtime.h>
#include <hip/hip_bf16.h>

#define VOCAB 200000
#define EDIM  256

typedef __attribute__((ext_vector_type(4))) float  f32x4;
typedef __attribute__((ext_vector_type(8))) __bf16 bf16x8;

__device__ __forceinline__ __bf16 f2bf(float f) {
    unsigned u = __builtin_bit_cast(unsigned, f);
    u += 0x7FFFu + ((u >> 16) & 1u);           // round-to-nearest-even
    unsigned short s = (unsigned short)(u >> 16);
    return __builtin_bit_cast(__bf16, s);
}

// Pack B into MFMA fragment order (verified correct in round 1).
// k = a*16 + b;  B[k][j] = core1[b, j, a], core1 is (16,256,16).
// bpk[(kk*16 + nt)*64 + lane] : lane l elem e = B[kk*32 + (l>>4)*8 + e][nt*16 + (l&15)]
__global__ void pack_b_kernel(const float* __restrict__ core1, bf16x8* __restrict__ bpk) {
    int t    = blockIdx.x * 256 + threadIdx.x;   // 0..8191
    int lane = t & 63;
    int nt   = (t >> 6) & 15;
    int kk   = t >> 10;
    int j     = nt * 16 + (lane & 15);
    int kbase = kk * 32 + ((lane >> 4) * 8);
    bf16x8 v;
#pragma unroll
    for (int e = 0; e < 8; ++e) {
        int k = kbase + e;
        int b = k & 15, a = k >> 4;
        v[e] = f2bf(core1[(b * 256 + j) * 16 + a]);
    }
    bpk[t] = v;
}

// Block = 512 threads (8 waves). Each block: 128 gathered rows x 128 output cols
// (colHalf selects cols 0..127 or 128..255). B half staged once into 64 KB LDS
// (lgkmcnt path); A gather register-pipelined depth-3 (vmcnt path) -> streams
// are decoupled, no per-k-step HBM-latency exposure.
__global__ __launch_bounds__(512, 4) void tr_embed_kernel(
        const int* __restrict__ x, const float* __restrict__ core0,
        const bf16x8* __restrict__ bpk, float* __restrict__ out) {
    __shared__ bf16x8 smem[4096];               // 64 KB: [kk 0..7][ntl 0..7][lane 0..63]
    const int tid  = threadIdx.x;
    const int lane = tid & 63;
    const int wave = tid >> 6;                  // 0..7
    const int bid  = blockIdx.x;
    const int rowTile = bid >> 1;
    const int colHalf = bid & 1;

    const int rowBase = rowTile * 128 + wave * 16;
    const int idx = x[rowBase + (lane & 15)];   // issue early (hides under staging)

    // Stage this block's B half: 4096 frags * 16 B, coalesced global reads.
#pragma unroll
    for (int i = 0; i < 8; ++i) {
        int e   = i * 512 + tid;                // 0..4095
        int kk  = e >> 9;
        int ntl = (e >> 6) & 7;
        int ln  = e & 63;
        smem[e] = bpk[(kk * 16 + colHalf * 8 + ntl) * 64 + ln];
    }

    // A gather pointers: k = a*16+b, k-step kk covers a = 2kk + (half>>1), b = (half&1)*8 + e
    const int half = lane >> 4;                 // 0..3
    const float* aptr = core0 + ((long)(half >> 1) * VOCAB + idx) * 16 + (half & 1) * 8;
    const int KST = 2 * VOCAB * 16;             // floats per k-step (a advances by 2)

    // Issue the first 3 k-steps' A loads before the barrier (fly during drain).
    f32x4 pa[3], pb[3];
#pragma unroll
    for (int k = 0; k < 3; ++k) {
        pa[k] = *(const f32x4*)(aptr + (long)k * KST);
        pb[k] = *(const f32x4*)(aptr + (long)k * KST + 4);
    }

    __syncthreads();

    f32x4 acc[8] = {};
#pragma unroll
    for (int kk = 0; kk < 8; ++kk) {
        const int s = kk % 3;                   // static after full unroll
        f32x4 ca = pa[s], cb = pb[s];
        if (kk + 3 < 8) {                       // rolling depth-3 prefetch
            pa[s] = *(const f32x4*)(aptr + (long)(kk + 3) * KST);
            pb[s] = *(const f32x4*)(aptr + (long)(kk + 3) * KST + 4);
        }
        bf16x8 af;
#pragma unroll
        for (int e = 0; e < 4; ++e) { af[e] = f2bf(ca[e]); af[e + 4] = f2bf(cb[e]); }

        const bf16x8* bs = smem + kk * 512 + lane;
#pragma unroll
        for (int ntl = 0; ntl < 8; ++ntl)
            acc[ntl] = __builtin_amdgcn_mfma_f32_16x16x32_bf16(af, bs[ntl * 64], acc[ntl], 0, 0, 0);
    }

    // C/D layout: col = lane&15, row = (lane>>4)*4 + reg (verified round 1)
    float* obase = out + (long)rowBase * 256 + colHalf * 128 + (lane & 15);
#pragma unroll
    for (int ntl = 0; ntl < 8; ++ntl) {
#pragma unroll
        for (int e = 0; e < 4; ++e) {
            obase[(half * 4 + e) * 256 + ntl * 16] = acc[ntl][e];
        }
    }
}

extern "C" void kernel_launch(void* const* d_in, const int* in_sizes, int n_in,
                              void* d_out, int out_size, void* d_ws, size_t ws_size,
                              hipStream_t stream) {
    const int*   x     = (const int*)d_in[0];
    const float* core0 = (const float*)d_in[1];
    const float* core1 = (const float*)d_in[2];
    float* out = (float*)d_out;
    bf16x8* bpk = (bf16x8*)d_ws;                // 128 KB scratch

    pack_b_kernel<<<32, 256, 0, stream>>>(core1, bpk);
    // 204800 rows / 128 rows-per-block * 2 col-halves = 3200 blocks
    tr_embed_kernel<<<3200, 512, 0, stream>>>(x, core0, bpk, out);
}

// Round 4
// 132.191 us; speedup vs baseline: 1.4543x; 1.2634x over previous
//
#include <hip/hip_runtime.h>
#include <hip/hip_bf16.h>

#define VOCAB 200000
#define EDIM  256

typedef __attribute__((ext_vector_type(4))) float  f32x4;
typedef __attribute__((ext_vector_type(8))) __bf16 bf16x8;

__device__ __forceinline__ __bf16 f2bf(float f) {
    unsigned u = __builtin_bit_cast(unsigned, f);
    u += 0x7FFFu + ((u >> 16) & 1u);           // round-to-nearest-even
    unsigned short s = (unsigned short)(u >> 16);
    return __builtin_bit_cast(__bf16, s);
}

// Pack B into MFMA fragment order (verified round 1).
// k = a*16 + b;  B[k][j] = core1[b, j, a], core1 is (16,256,16).
// bpk[(kk*16 + nt)*64 + lane] : lane l elem e = B[kk*32 + (l>>4)*8 + e][nt*16 + (l&15)]
__global__ void pack_b_kernel(const float* __restrict__ core1, bf16x8* __restrict__ bpk) {
    int t    = blockIdx.x * 256 + threadIdx.x;   // 0..8191
    int lane = t & 63;
    int nt   = (t >> 6) & 15;
    int kk   = t >> 10;
    int j     = nt * 16 + (lane & 15);
    int kbase = kk * 32 + ((lane >> 4) * 8);
    bf16x8 v;
#pragma unroll
    for (int e = 0; e < 8; ++e) {
        int k = kbase + e;
        int b = k & 15, a = k >> 4;
        v[e] = f2bf(core1[(b * 256 + j) * 16 + a]);
    }
    bpk[t] = v;
}

// Block = 512 threads (8 waves): 128 gathered rows x 128 output cols.
// Grid = 3200 = 8 XCDs * 400 slots; the two col-halves of each rowTile sit at
// adjacent slots on the SAME XCD -> second half's A-gather hits that XCD's L2.
// All 8 k-steps' A loads issued up front (16 scattered dwordx4 per lane)
// -> ~8 KB in flight per CU, enough for ~5.5 TB/s by Little's law.
__global__ __launch_bounds__(512, 4) void tr_embed_kernel(
        const int* __restrict__ x, const float* __restrict__ core0,
        const bf16x8* __restrict__ bpk, float* __restrict__ out) {
    __shared__ bf16x8 smem[4096];               // 64 KB: [kk 0..7][ntl 0..7][lane 0..63]
    const int tid  = threadIdx.x;
    const int lane = tid & 63;
    const int wave = tid >> 6;                  // 0..7

    // grid = 3200 = 8 XCDs * 400 slots (round-robin bid->XCD assumed; perf-only)
    const int xcd  = blockIdx.x & 7;
    const int slot = blockIdx.x >> 3;           // 0..399 on this XCD
    const int rowTile = xcd * 200 + (slot >> 1);  // 0..1599
    const int colHalf = slot & 1;

    const int rowBase = rowTile * 128 + wave * 16;   // < 204800
    const int idx = x[rowBase + (lane & 15)];   // issue early

    // Stage this block's B half: 4096 frags * 16 B, coalesced global reads.
#pragma unroll
    for (int i = 0; i < 8; ++i) {
        int e   = i * 512 + tid;                // 0..4095
        int kk  = e >> 9;
        int ntl = (e >> 6) & 7;
        int ln  = e & 63;
        smem[e] = bpk[(kk * 16 + colHalf * 8 + ntl) * 64 + ln];
    }

    // A gather: k = a*16+b; k-step kk covers a = 2kk + (half>>1), b = (half&1)*8 + e
    const int half = lane >> 4;                 // 0..3
    const float* aptr = core0 + ((long)(half >> 1) * VOCAB + idx) * 16 + (half & 1) * 8;
    const int KST = 2 * VOCAB * 16;             // floats per k-step (a advances by 2)

    // Issue ALL 8 k-steps' A loads up front (full-depth pipeline).
    f32x4 pa[8], pb[8];
#pragma unroll
    for (int k = 0; k < 8; ++k) {
        pa[k] = *(const f32x4*)(aptr + (long)k * KST);
        pb[k] = *(const f32x4*)(aptr + (long)k * KST + 4);
    }

    __syncthreads();

    f32x4 acc[8] = {};
#pragma unroll
    for (int kk = 0; kk < 8; ++kk) {
        bf16x8 af;
#pragma unroll
        for (int e = 0; e < 4; ++e) { af[e] = f2bf(pa[kk][e]); af[e + 4] = f2bf(pb[kk][e]); }

        const bf16x8* bs = smem + kk * 512 + lane;
#pragma unroll
        for (int ntl = 0; ntl < 8; ++ntl)
            acc[ntl] = __builtin_amdgcn_mfma_f32_16x16x32_bf16(af, bs[ntl * 64], acc[ntl], 0, 0, 0);
    }

    // C/D layout: col = lane&15, row = (lane>>4)*4 + reg (verified)
    float* obase = out + (long)rowBase * 256 + colHalf * 128 + (lane & 15);
#pragma unroll
    for (int ntl = 0; ntl < 8; ++ntl) {
#pragma unroll
        for (int e = 0; e < 4; ++e) {
            obase[(half * 4 + e) * 256 + ntl * 16] = acc[ntl][e];
        }
    }
}

extern "C" void kernel_launch(void* const* d_in, const int* in_sizes, int n_in,
                              void* d_out, int out_size, void* d_ws, size_t ws_size,
                              hipStream_t stream) {
    const int*   x     = (const int*)d_in[0];
    const float* core0 = (const float*)d_in[1];
    const float* core1 = (const float*)d_in[2];
    float* out = (float*)d_out;
    bf16x8* bpk = (bf16x8*)d_ws;                // 128 KB scratch

    pack_b_kernel<<<32, 256, 0, stream>>>(core1, bpk);
    // 1600 rowTiles * 2 col-halves = 3200 blocks (= 8 XCDs * 400 slots)
    tr_embed_kernel<<<3200, 512, 0, stream>>>(x, core0, bpk, out);
}